// Round 1
// baseline (1047.626 us; speedup 1.0000x reference)
//
#include <hip/hip_runtime.h>
#include <hip/hip_bf16.h>

#define N_NODES 50000
#define N_EDGES 800000
#define HIDDEN  256
#define N_GRAPHS 128

// ---------------- degree / norm ----------------
__global__ void deg_count_kernel(const int* __restrict__ ei, int* __restrict__ deg) {
    int e = blockIdx.x * blockDim.x + threadIdx.x;
    if (e < N_EDGES) {
        int dst = ei[N_EDGES + e];
        atomicAdd(&deg[dst], 1);
    }
}

__global__ void dinv_kernel(const int* __restrict__ deg, float* __restrict__ dinv) {
    int i = blockIdx.x * blockDim.x + threadIdx.x;
    if (i < N_NODES) dinv[i] = rsqrtf((float)(deg[i] + 1)); // +1 = self loop
}

// single-block chunked inclusive scan -> exclusive rowptr
__global__ void scan_kernel(const int* __restrict__ deg, int* __restrict__ rowptr) {
    __shared__ int sdata[1024];
    __shared__ int sbase;
    int tid = threadIdx.x;
    if (tid == 0) { sbase = 0; rowptr[0] = 0; }
    __syncthreads();
    for (int chunk = 0; chunk < N_NODES; chunk += 1024) {
        int i = chunk + tid;
        int v = (i < N_NODES) ? deg[i] : 0;
        sdata[tid] = v;
        __syncthreads();
        for (int ofs = 1; ofs < 1024; ofs <<= 1) {
            int t = (tid >= ofs) ? sdata[tid - ofs] : 0;
            __syncthreads();
            sdata[tid] += t;
            __syncthreads();
        }
        if (i < N_NODES) rowptr[i + 1] = sbase + sdata[tid];
        __syncthreads();
        if (tid == 0) sbase += sdata[1023];
        __syncthreads();
    }
}

__global__ void fill_csr_kernel(const int* __restrict__ ei, const int* __restrict__ rowptr,
                                int* __restrict__ cursor, const float* __restrict__ dinv,
                                int* __restrict__ csr_src, float* __restrict__ csr_norm) {
    int e = blockIdx.x * blockDim.x + threadIdx.x;
    if (e < N_EDGES) {
        int s = ei[e];
        int d = ei[N_EDGES + e];
        int p = rowptr[d] + atomicAdd(&cursor[d], 1);
        csr_src[p] = s;
        csr_norm[p] = dinv[s] * dinv[d];
    }
}

// ---------------- conv1: aggregate 2-ch x first, then expand ----------------
__global__ void aggx_kernel(const float* __restrict__ x, const int* __restrict__ rowptr,
                            const int* __restrict__ csr_src, const float* __restrict__ csr_norm,
                            const float* __restrict__ dinv, float* __restrict__ ax) {
    int i = blockIdx.x * blockDim.x + threadIdx.x;
    if (i >= N_NODES) return;
    float di = dinv[i];
    float w0 = di * di;
    float a0 = x[2 * i] * w0, a1 = x[2 * i + 1] * w0;
    int e0 = rowptr[i], e1 = rowptr[i + 1];
    for (int p = e0; p < e1; ++p) {
        int s = csr_src[p];
        float w = csr_norm[p];
        a0 += x[2 * s] * w;
        a1 += x[2 * s + 1] * w;
    }
    ax[2 * i] = a0;
    ax[2 * i + 1] = a1;
}

__global__ void expand1_kernel(const float* __restrict__ ax, const float* __restrict__ W1,
                               const float* __restrict__ b1, float* __restrict__ h) {
    int idx = blockIdx.x * blockDim.x + threadIdx.x;
    if (idx >= N_NODES * HIDDEN) return;
    int i = idx >> 8, c = idx & 255;
    h[idx] = ax[2 * i] * W1[c] + ax[2 * i + 1] * W1[HIDDEN + c] + b1[c];
}

// ---------------- dense GEMM: C = relu(A) @ B,  A[M,256], B[256,256] ----------------
#define BM 64
#define BN 64
#define BK 16
__global__ __launch_bounds__(256) void gemm_relu_kernel(const float* __restrict__ A,
                                                        const float* __restrict__ B,
                                                        float* __restrict__ C) {
    __shared__ float As[BK][BM + 1];
    __shared__ float Bs[BK][BN];
    int tid = threadIdx.x;
    int row0 = blockIdx.x * BM;
    int col0 = blockIdx.y * BN;
    int tx = tid & 15, ty = tid >> 4;
    int arow = tid >> 2, ak4 = (tid & 3) * 4;
    int brow = tid >> 4, bc4 = (tid & 15) * 4;

    float acc[4][4] = {};
    for (int k0 = 0; k0 < 256; k0 += BK) {
        float4 a4 = make_float4(0.f, 0.f, 0.f, 0.f);
        int gr = row0 + arow;
        if (gr < N_NODES) a4 = *(const float4*)&A[(size_t)gr * 256 + k0 + ak4];
        a4.x = fmaxf(a4.x, 0.f); a4.y = fmaxf(a4.y, 0.f);
        a4.z = fmaxf(a4.z, 0.f); a4.w = fmaxf(a4.w, 0.f);
        float4 b4 = *(const float4*)&B[(size_t)(k0 + brow) * 256 + col0 + bc4];
        __syncthreads();
        As[ak4 + 0][arow] = a4.x;
        As[ak4 + 1][arow] = a4.y;
        As[ak4 + 2][arow] = a4.z;
        As[ak4 + 3][arow] = a4.w;
        Bs[brow][bc4 + 0] = b4.x;
        Bs[brow][bc4 + 1] = b4.y;
        Bs[brow][bc4 + 2] = b4.z;
        Bs[brow][bc4 + 3] = b4.w;
        __syncthreads();
#pragma unroll
        for (int k = 0; k < BK; ++k) {
            float ar[4], br[4];
#pragma unroll
            for (int j = 0; j < 4; ++j) ar[j] = As[k][ty * 4 + j];
#pragma unroll
            for (int j = 0; j < 4; ++j) br[j] = Bs[k][tx * 4 + j];
#pragma unroll
            for (int i = 0; i < 4; ++i)
#pragma unroll
                for (int j = 0; j < 4; ++j) acc[i][j] += ar[i] * br[j];
        }
    }
#pragma unroll
    for (int i = 0; i < 4; ++i) {
        int gr = row0 + ty * 4 + i;
        if (gr < N_NODES) {
            float4 v = make_float4(acc[i][0], acc[i][1], acc[i][2], acc[i][3]);
            *(float4*)&C[(size_t)gr * 256 + col0 + tx * 4] = v;
        }
    }
}

// ---------------- aggregation: out[i,:] = sum_e t[src,:]*w + t[i,:]*dinv^2 + b ----------------
__global__ __launch_bounds__(256) void aggregate_kernel(const float* __restrict__ t,
                                                        const int* __restrict__ rowptr,
                                                        const int* __restrict__ csr_src,
                                                        const float* __restrict__ csr_norm,
                                                        const float* __restrict__ dinv,
                                                        const float* __restrict__ bias,
                                                        float* __restrict__ out) {
    int node = blockIdx.x * 4 + (threadIdx.x >> 6);
    if (node >= N_NODES) return;
    int lane = threadIdx.x & 63;
    int c = lane * 4;
    float di = dinv[node];
    float w0 = di * di;
    float4 v = *(const float4*)&t[(size_t)node * HIDDEN + c];
    float4 acc = make_float4(v.x * w0, v.y * w0, v.z * w0, v.w * w0);
    int e0 = rowptr[node], e1 = rowptr[node + 1];
    for (int p = e0; p < e1; ++p) {
        int s = csr_src[p];
        float w = csr_norm[p];
        float4 u = *(const float4*)&t[(size_t)s * HIDDEN + c];
        acc.x += u.x * w; acc.y += u.y * w; acc.z += u.z * w; acc.w += u.w * w;
    }
    float4 b4 = *(const float4*)&bias[c];
    acc.x += b4.x; acc.y += b4.y; acc.z += b4.z; acc.w += b4.w;
    *(float4*)&out[(size_t)node * HIDDEN + c] = acc;
}

// ---------------- pooling ----------------
__global__ void bounds_kernel(const int* __restrict__ batch, int* __restrict__ gbounds) {
    int i = blockIdx.x * blockDim.x + threadIdx.x;
    if (i >= N_NODES) return;
    int bi = batch[i];
    int bprev = (i == 0) ? -1 : batch[i - 1];
    for (int g = bprev + 1; g <= bi; ++g) gbounds[g] = i;
    if (i == N_NODES - 1) {
        for (int g = bi + 1; g <= N_GRAPHS; ++g) gbounds[g] = N_NODES;
    }
}

__global__ __launch_bounds__(256) void pool_kernel(const float* __restrict__ h,
                                                   const int* __restrict__ gbounds,
                                                   float* __restrict__ gsum) {
    int g = blockIdx.x;
    int c = threadIdx.x;
    int s = gbounds[g], e = gbounds[g + 1];
    float acc = 0.f;
    for (int i = s; i < e; ++i) acc += h[(size_t)i * HIDDEN + c];
    float cnt = (float)(e - s);
    gsum[g * HIDDEN + c] = acc / fmaxf(cnt, 1.f);
}

// ---------------- MLP head ----------------
__global__ __launch_bounds__(128) void mlp_kernel(const float* __restrict__ gsum,
                                                  const float* __restrict__ lin1_w,
                                                  const float* __restrict__ lin1_b,
                                                  const float* __restrict__ lin2_w,
                                                  const float* __restrict__ lin2_b,
                                                  float* __restrict__ out) {
    __shared__ float grow[HIDDEN];
    __shared__ float red[2];
    int g = blockIdx.x, j = threadIdx.x;
    grow[j] = gsum[g * HIDDEN + j];
    grow[j + 128] = gsum[g * HIDDEN + j + 128];
    __syncthreads();
    float acc = lin1_b[j];
    for (int k = 0; k < HIDDEN; ++k) acc += grow[k] * lin1_w[k * 128 + j];
    acc = fmaxf(acc, 0.f);
    float v = acc * lin2_w[j];
#pragma unroll
    for (int ofs = 32; ofs > 0; ofs >>= 1) v += __shfl_down(v, ofs, 64);
    if ((j & 63) == 0) red[j >> 6] = v;
    __syncthreads();
    if (j == 0) out[g] = red[0] + red[1] + lin2_b[0];
}

// ---------------- launch ----------------
extern "C" void kernel_launch(void* const* d_in, const int* in_sizes, int n_in,
                              void* d_out, int out_size, void* d_ws, size_t ws_size,
                              hipStream_t stream) {
    const float* x      = (const float*)d_in[0];
    const int*   ei     = (const int*)d_in[1];
    const int*   batch  = (const int*)d_in[2];
    const float* W1     = (const float*)d_in[3];
    const float* b1     = (const float*)d_in[4];
    const float* W2     = (const float*)d_in[5];
    const float* b2     = (const float*)d_in[6];
    const float* W3     = (const float*)d_in[7];
    const float* b3     = (const float*)d_in[8];
    const float* W4     = (const float*)d_in[9];
    const float* b4     = (const float*)d_in[10];
    const float* lin1_w = (const float*)d_in[11];
    const float* lin1_b = (const float*)d_in[12];
    const float* lin2_w = (const float*)d_in[13];
    const float* lin2_b = (const float*)d_in[14];
    float* out = (float*)d_out;

    char* ws = (char*)d_ws;
    size_t off = 0;
    auto alloc = [&](size_t bytes) -> void* {
        void* p = ws + off;
        off += (bytes + 255) & ~(size_t)255;
        return p;
    };
    float* bufA     = (float*)alloc((size_t)N_NODES * HIDDEN * 4);  // 51.2 MB
    float* bufB     = (float*)alloc((size_t)N_NODES * HIDDEN * 4);  // 51.2 MB
    float* csr_norm = (float*)alloc((size_t)N_EDGES * 4);
    int*   csr_src  = (int*)alloc((size_t)N_EDGES * 4);
    int*   rowptr   = (int*)alloc((size_t)(N_NODES + 1) * 4);
    int*   deg      = (int*)alloc((size_t)N_NODES * 4);
    int*   cursor   = (int*)alloc((size_t)N_NODES * 4);
    float* dinv     = (float*)alloc((size_t)N_NODES * 4);
    float* ax       = (float*)alloc((size_t)N_NODES * 2 * 4);
    float* gsum     = (float*)alloc((size_t)N_GRAPHS * HIDDEN * 4);
    int*   gbounds  = (int*)alloc((size_t)(N_GRAPHS + 1) * 4);

    hipMemsetAsync(deg, 0, (size_t)N_NODES * 4, stream);
    hipMemsetAsync(cursor, 0, (size_t)N_NODES * 4, stream);

    const int TB = 256;
    deg_count_kernel<<<(N_EDGES + TB - 1) / TB, TB, 0, stream>>>(ei, deg);
    dinv_kernel<<<(N_NODES + TB - 1) / TB, TB, 0, stream>>>(deg, dinv);
    scan_kernel<<<1, 1024, 0, stream>>>(deg, rowptr);
    fill_csr_kernel<<<(N_EDGES + TB - 1) / TB, TB, 0, stream>>>(ei, rowptr, cursor, dinv,
                                                                csr_src, csr_norm);

    // conv1: (A x) W1 + b1
    aggx_kernel<<<(N_NODES + TB - 1) / TB, TB, 0, stream>>>(x, rowptr, csr_src, csr_norm, dinv, ax);
    expand1_kernel<<<(N_NODES * HIDDEN) / TB, TB, 0, stream>>>(ax, W1, b1, bufA);

    // conv2..4
    dim3 ggrid((N_NODES + BM - 1) / BM, HIDDEN / BN);
    const float* Ws[3] = {W2, W3, W4};
    const float* bs[3] = {b2, b3, b4};
    for (int l = 0; l < 3; ++l) {
        gemm_relu_kernel<<<ggrid, 256, 0, stream>>>(bufA, Ws[l], bufB);
        aggregate_kernel<<<(N_NODES + 3) / 4, 256, 0, stream>>>(bufB, rowptr, csr_src, csr_norm,
                                                                dinv, bs[l], bufA);
    }

    // pooling + head
    bounds_kernel<<<(N_NODES + TB - 1) / TB, TB, 0, stream>>>(batch, gbounds);
    pool_kernel<<<N_GRAPHS, 256, 0, stream>>>(bufA, gbounds, gsum);
    mlp_kernel<<<N_GRAPHS, 128, 0, stream>>>(gsum, lin1_w, lin1_b, lin2_w, lin2_b, out);
}

// Round 2
// 901.346 us; speedup vs baseline: 1.1623x; 1.1623x over previous
//
#include <hip/hip_runtime.h>
#include <hip/hip_bf16.h>

#define N_NODES 50000
#define N_EDGES 800000
#define HIDDEN  256
#define N_GRAPHS 128

// ---------------- degree / norm ----------------
__global__ void deg_count_kernel(const int* __restrict__ ei, int* __restrict__ deg) {
    int e = blockIdx.x * blockDim.x + threadIdx.x;
    if (e < N_EDGES) {
        int dst = ei[N_EDGES + e];
        atomicAdd(&deg[dst], 1);
    }
}

__global__ void dinv_kernel(const int* __restrict__ deg, float* __restrict__ dinv) {
    int i = blockIdx.x * blockDim.x + threadIdx.x;
    if (i < N_NODES) dinv[i] = rsqrtf((float)(deg[i] + 1)); // +1 = self loop
}

// ---------------- hierarchical scan: rowptr = exclusive-scan(deg) ----------------
__global__ __launch_bounds__(256) void block_scan_kernel(const int* __restrict__ deg,
                                                         int* __restrict__ rowptr,
                                                         int* __restrict__ bsums) {
    __shared__ int s[256];
    int tid = threadIdx.x;
    int i = blockIdx.x * 256 + tid;
    int v = (i < N_NODES) ? deg[i] : 0;
    s[tid] = v;
    __syncthreads();
#pragma unroll
    for (int ofs = 1; ofs < 256; ofs <<= 1) {
        int t = (tid >= ofs) ? s[tid - ofs] : 0;
        __syncthreads();
        s[tid] += t;
        __syncthreads();
    }
    if (i < N_NODES) rowptr[i + 1] = s[tid]; // partial inclusive within block
    if (tid == 255) bsums[blockIdx.x] = s[255];
}

__global__ __launch_bounds__(256) void scan_bsums_kernel(int* __restrict__ bsums, int nb) {
    __shared__ int s[256];
    int tid = threadIdx.x;
    int v = (tid < nb) ? bsums[tid] : 0;
    s[tid] = v;
    __syncthreads();
#pragma unroll
    for (int ofs = 1; ofs < 256; ofs <<= 1) {
        int t = (tid >= ofs) ? s[tid - ofs] : 0;
        __syncthreads();
        s[tid] += t;
        __syncthreads();
    }
    if (tid < nb) bsums[tid] = (tid == 0) ? 0 : s[tid - 1]; // exclusive
}

__global__ __launch_bounds__(256) void add_offsets_kernel(int* __restrict__ rowptr,
                                                          const int* __restrict__ bsums) {
    int i = blockIdx.x * 256 + threadIdx.x;
    if (i == 0) rowptr[0] = 0;
    if (i < N_NODES) rowptr[i + 1] += bsums[blockIdx.x];
}

__global__ void fill_csr_kernel(const int* __restrict__ ei, const int* __restrict__ rowptr,
                                int* __restrict__ cursor, const float* __restrict__ dinv,
                                int* __restrict__ csr_src, float* __restrict__ csr_norm) {
    int e = blockIdx.x * blockDim.x + threadIdx.x;
    if (e < N_EDGES) {
        int s = ei[e];
        int d = ei[N_EDGES + e];
        int p = rowptr[d] + atomicAdd(&cursor[d], 1);
        csr_src[p] = s;
        csr_norm[p] = dinv[s] * dinv[d];
    }
}

// ---------------- conv1: aggregate 2-ch x first, then expand ----------------
__global__ void aggx_kernel(const float* __restrict__ x, const int* __restrict__ rowptr,
                            const int* __restrict__ csr_src, const float* __restrict__ csr_norm,
                            const float* __restrict__ dinv, float* __restrict__ ax) {
    int i = blockIdx.x * blockDim.x + threadIdx.x;
    if (i >= N_NODES) return;
    float di = dinv[i];
    float w0 = di * di;
    float a0 = x[2 * i] * w0, a1 = x[2 * i + 1] * w0;
    int e0 = rowptr[i], e1 = rowptr[i + 1];
    for (int p = e0; p < e1; ++p) {
        int s = csr_src[p];
        float w = csr_norm[p];
        a0 += x[2 * s] * w;
        a1 += x[2 * s + 1] * w;
    }
    ax[2 * i] = a0;
    ax[2 * i + 1] = a1;
}

__global__ void expand1_kernel(const float* __restrict__ ax, const float* __restrict__ W1,
                               const float* __restrict__ b1, float* __restrict__ h) {
    int idx = blockIdx.x * blockDim.x + threadIdx.x;
    if (idx >= N_NODES * HIDDEN) return;
    int i = idx >> 8, c = idx & 255;
    h[idx] = ax[2 * i] * W1[c] + ax[2 * i + 1] * W1[HIDDEN + c] + b1[c];
}

// ---------------- dense GEMM: C = relu(A) @ B,  A[M,256], B[256,256] ----------------
// 128x128 tile, 8 k-slice, 256 threads, 8x8 acc/thread (split +-64 mapping).
#define GBM 128
#define GBN 128
#define GBK 8
__global__ __launch_bounds__(256) void gemm_relu_kernel(const float* __restrict__ A,
                                                        const float* __restrict__ B,
                                                        float* __restrict__ C) {
    __shared__ float As[GBK][GBM]; // transposed: As[k][m]
    __shared__ float Bs[GBK][GBN];
    int tid = threadIdx.x;
    int row0 = blockIdx.x * GBM;
    int col0 = blockIdx.y * GBN;

    // staging mapping: one float4 of A + one float4 of B per thread per tile
    int arow = tid >> 1;             // 0..127
    int akq  = (tid & 1) * 4;        // 0 or 4
    int brow = tid >> 5;             // 0..7
    int bcol = (tid & 31) * 4;       // 0..124

    int gr = row0 + arow;
    bool arow_ok = (gr < N_NODES);
    const float* Aptr = A + (size_t)(arow_ok ? gr : 0) * 256; // clamped; garbage rows never stored

    int tx = tid & 15, ty = tid >> 4;

    float acc[8][8];
#pragma unroll
    for (int i = 0; i < 8; ++i)
#pragma unroll
        for (int j = 0; j < 8; ++j) acc[i][j] = 0.f;

    float4 a4 = *(const float4*)&Aptr[akq];
    float4 b4 = *(const float4*)&B[(size_t)brow * 256 + col0 + bcol];

    for (int k0 = 0; k0 < 256; k0 += GBK) {
        __syncthreads(); // prev iter done reading LDS
        As[akq + 0][arow] = fmaxf(a4.x, 0.f);
        As[akq + 1][arow] = fmaxf(a4.y, 0.f);
        As[akq + 2][arow] = fmaxf(a4.z, 0.f);
        As[akq + 3][arow] = fmaxf(a4.w, 0.f);
        *(float4*)&Bs[brow][bcol] = b4;
        __syncthreads();
        if (k0 + GBK < 256) {
            a4 = *(const float4*)&Aptr[k0 + GBK + akq];
            b4 = *(const float4*)&B[(size_t)(k0 + GBK + brow) * 256 + col0 + bcol];
        }
#pragma unroll
        for (int k = 0; k < GBK; ++k) {
            float ar[8], br[8];
            *(float4*)&ar[0] = *(const float4*)&As[k][ty * 4];
            *(float4*)&ar[4] = *(const float4*)&As[k][64 + ty * 4];
            *(float4*)&br[0] = *(const float4*)&Bs[k][tx * 4];
            *(float4*)&br[4] = *(const float4*)&Bs[k][64 + tx * 4];
#pragma unroll
            for (int i = 0; i < 8; ++i)
#pragma unroll
                for (int j = 0; j < 8; ++j) acc[i][j] += ar[i] * br[j];
        }
    }

#pragma unroll
    for (int ih = 0; ih < 2; ++ih)
#pragma unroll
        for (int i = 0; i < 4; ++i) {
            int r = row0 + ih * 64 + ty * 4 + i;
            if (r < N_NODES) {
                float* crow = &C[(size_t)r * 256 + col0];
                *(float4*)&crow[tx * 4] =
                    make_float4(acc[ih * 4 + i][0], acc[ih * 4 + i][1],
                                acc[ih * 4 + i][2], acc[ih * 4 + i][3]);
                *(float4*)&crow[64 + tx * 4] =
                    make_float4(acc[ih * 4 + i][4], acc[ih * 4 + i][5],
                                acc[ih * 4 + i][6], acc[ih * 4 + i][7]);
            }
        }
}

// ---------------- aggregation: out[i,:] = sum_e t[src,:]*w + t[i,:]*dinv^2 + b ----------------
__global__ __launch_bounds__(256) void aggregate_kernel(const float* __restrict__ t,
                                                        const int* __restrict__ rowptr,
                                                        const int* __restrict__ csr_src,
                                                        const float* __restrict__ csr_norm,
                                                        const float* __restrict__ dinv,
                                                        const float* __restrict__ bias,
                                                        float* __restrict__ out) {
    int node = blockIdx.x * 4 + (threadIdx.x >> 6);
    if (node >= N_NODES) return;
    int lane = threadIdx.x & 63;
    int c = lane * 4;
    float di = dinv[node];
    float w0 = di * di;
    float4 v = *(const float4*)&t[(size_t)node * HIDDEN + c];
    float4 acc = make_float4(v.x * w0, v.y * w0, v.z * w0, v.w * w0);
    int e0 = rowptr[node], e1 = rowptr[node + 1];
    int p = e0;
    // unroll x4: 4 independent gathers in flight per lane
    for (; p + 4 <= e1; p += 4) {
        int s0 = csr_src[p + 0], s1 = csr_src[p + 1];
        int s2 = csr_src[p + 2], s3 = csr_src[p + 3];
        float n0 = csr_norm[p + 0], n1 = csr_norm[p + 1];
        float n2 = csr_norm[p + 2], n3 = csr_norm[p + 3];
        float4 u0 = *(const float4*)&t[(size_t)s0 * HIDDEN + c];
        float4 u1 = *(const float4*)&t[(size_t)s1 * HIDDEN + c];
        float4 u2 = *(const float4*)&t[(size_t)s2 * HIDDEN + c];
        float4 u3 = *(const float4*)&t[(size_t)s3 * HIDDEN + c];
        acc.x += u0.x * n0; acc.y += u0.y * n0; acc.z += u0.z * n0; acc.w += u0.w * n0;
        acc.x += u1.x * n1; acc.y += u1.y * n1; acc.z += u1.z * n1; acc.w += u1.w * n1;
        acc.x += u2.x * n2; acc.y += u2.y * n2; acc.z += u2.z * n2; acc.w += u2.w * n2;
        acc.x += u3.x * n3; acc.y += u3.y * n3; acc.z += u3.z * n3; acc.w += u3.w * n3;
    }
    for (; p < e1; ++p) {
        int s = csr_src[p];
        float w = csr_norm[p];
        float4 u = *(const float4*)&t[(size_t)s * HIDDEN + c];
        acc.x += u.x * w; acc.y += u.y * w; acc.z += u.z * w; acc.w += u.w * w;
    }
    float4 b4 = *(const float4*)&bias[c];
    acc.x += b4.x; acc.y += b4.y; acc.z += b4.z; acc.w += b4.w;
    *(float4*)&out[(size_t)node * HIDDEN + c] = acc;
}

// ---------------- pooling ----------------
__global__ void bounds_kernel(const int* __restrict__ batch, int* __restrict__ gbounds) {
    int i = blockIdx.x * blockDim.x + threadIdx.x;
    if (i >= N_NODES) return;
    int bi = batch[i];
    int bprev = (i == 0) ? -1 : batch[i - 1];
    for (int g = bprev + 1; g <= bi; ++g) gbounds[g] = i;
    if (i == N_NODES - 1) {
        for (int g = bi + 1; g <= N_GRAPHS; ++g) gbounds[g] = N_NODES;
    }
}

__global__ __launch_bounds__(256) void pool_kernel(const float* __restrict__ h,
                                                   const int* __restrict__ gbounds,
                                                   float* __restrict__ gsum) {
    int g = blockIdx.x;
    int c = threadIdx.x;
    int s = gbounds[g], e = gbounds[g + 1];
    float acc = 0.f;
    int i = s;
    for (; i + 4 <= e; i += 4) {
        float v0 = h[(size_t)(i + 0) * HIDDEN + c];
        float v1 = h[(size_t)(i + 1) * HIDDEN + c];
        float v2 = h[(size_t)(i + 2) * HIDDEN + c];
        float v3 = h[(size_t)(i + 3) * HIDDEN + c];
        acc += v0 + v1 + v2 + v3;
    }
    for (; i < e; ++i) acc += h[(size_t)i * HIDDEN + c];
    float cnt = (float)(e - s);
    gsum[g * HIDDEN + c] = acc / fmaxf(cnt, 1.f);
}

// ---------------- MLP head ----------------
__global__ __launch_bounds__(128) void mlp_kernel(const float* __restrict__ gsum,
                                                  const float* __restrict__ lin1_w,
                                                  const float* __restrict__ lin1_b,
                                                  const float* __restrict__ lin2_w,
                                                  const float* __restrict__ lin2_b,
                                                  float* __restrict__ out) {
    __shared__ float grow[HIDDEN];
    __shared__ float red[2];
    int g = blockIdx.x, j = threadIdx.x;
    grow[j] = gsum[g * HIDDEN + j];
    grow[j + 128] = gsum[g * HIDDEN + j + 128];
    __syncthreads();
    float acc = lin1_b[j];
    for (int k = 0; k < HIDDEN; ++k) acc += grow[k] * lin1_w[k * 128 + j];
    acc = fmaxf(acc, 0.f);
    float v = acc * lin2_w[j];
#pragma unroll
    for (int ofs = 32; ofs > 0; ofs >>= 1) v += __shfl_down(v, ofs, 64);
    if ((j & 63) == 0) red[j >> 6] = v;
    __syncthreads();
    if (j == 0) out[g] = red[0] + red[1] + lin2_b[0];
}

// ---------------- launch ----------------
extern "C" void kernel_launch(void* const* d_in, const int* in_sizes, int n_in,
                              void* d_out, int out_size, void* d_ws, size_t ws_size,
                              hipStream_t stream) {
    const float* x      = (const float*)d_in[0];
    const int*   ei     = (const int*)d_in[1];
    const int*   batch  = (const int*)d_in[2];
    const float* W1     = (const float*)d_in[3];
    const float* b1     = (const float*)d_in[4];
    const float* W2     = (const float*)d_in[5];
    const float* b2     = (const float*)d_in[6];
    const float* W3     = (const float*)d_in[7];
    const float* b3     = (const float*)d_in[8];
    const float* W4     = (const float*)d_in[9];
    const float* b4     = (const float*)d_in[10];
    const float* lin1_w = (const float*)d_in[11];
    const float* lin1_b = (const float*)d_in[12];
    const float* lin2_w = (const float*)d_in[13];
    const float* lin2_b = (const float*)d_in[14];
    float* out = (float*)d_out;

    char* ws = (char*)d_ws;
    size_t off = 0;
    auto alloc = [&](size_t bytes) -> void* {
        void* p = ws + off;
        off += (bytes + 255) & ~(size_t)255;
        return p;
    };
    float* bufA     = (float*)alloc((size_t)N_NODES * HIDDEN * 4);  // 51.2 MB
    float* bufB     = (float*)alloc((size_t)N_NODES * HIDDEN * 4);  // 51.2 MB
    float* csr_norm = (float*)alloc((size_t)N_EDGES * 4);
    int*   csr_src  = (int*)alloc((size_t)N_EDGES * 4);
    int*   rowptr   = (int*)alloc((size_t)(N_NODES + 1) * 4);
    int*   deg      = (int*)alloc((size_t)N_NODES * 4);
    int*   cursor   = (int*)alloc((size_t)N_NODES * 4);
    float* dinv     = (float*)alloc((size_t)N_NODES * 4);
    float* ax       = (float*)alloc((size_t)N_NODES * 2 * 4);
    float* gsum     = (float*)alloc((size_t)N_GRAPHS * HIDDEN * 4);
    int*   gbounds  = (int*)alloc((size_t)(N_GRAPHS + 1) * 4);
    int*   bsums    = (int*)alloc((size_t)256 * 4);

    hipMemsetAsync(deg, 0, (size_t)N_NODES * 4, stream);
    hipMemsetAsync(cursor, 0, (size_t)N_NODES * 4, stream);

    const int TB = 256;
    const int NBLK = (N_NODES + 255) / 256; // 196
    deg_count_kernel<<<(N_EDGES + TB - 1) / TB, TB, 0, stream>>>(ei, deg);
    dinv_kernel<<<(N_NODES + TB - 1) / TB, TB, 0, stream>>>(deg, dinv);
    block_scan_kernel<<<NBLK, 256, 0, stream>>>(deg, rowptr, bsums);
    scan_bsums_kernel<<<1, 256, 0, stream>>>(bsums, NBLK);
    add_offsets_kernel<<<NBLK, 256, 0, stream>>>(rowptr, bsums);
    fill_csr_kernel<<<(N_EDGES + TB - 1) / TB, TB, 0, stream>>>(ei, rowptr, cursor, dinv,
                                                                csr_src, csr_norm);

    // conv1: (A x) W1 + b1
    aggx_kernel<<<(N_NODES + TB - 1) / TB, TB, 0, stream>>>(x, rowptr, csr_src, csr_norm, dinv, ax);
    expand1_kernel<<<(N_NODES * HIDDEN) / TB, TB, 0, stream>>>(ax, W1, b1, bufA);

    // conv2..4
    dim3 ggrid((N_NODES + GBM - 1) / GBM, HIDDEN / GBN);
    const float* Ws[3] = {W2, W3, W4};
    const float* bs[3] = {b2, b3, b4};
    for (int l = 0; l < 3; ++l) {
        gemm_relu_kernel<<<ggrid, 256, 0, stream>>>(bufA, Ws[l], bufB);
        aggregate_kernel<<<(N_NODES + 3) / 4, 256, 0, stream>>>(bufB, rowptr, csr_src, csr_norm,
                                                                dinv, bs[l], bufA);
    }

    // pooling + head
    bounds_kernel<<<(N_NODES + TB - 1) / TB, TB, 0, stream>>>(batch, gbounds);
    pool_kernel<<<N_GRAPHS, 256, 0, stream>>>(bufA, gbounds, gsum);
    mlp_kernel<<<N_GRAPHS, 128, 0, stream>>>(gsum, lin1_w, lin1_b, lin2_w, lin2_b, out);
}